// Round 1
// baseline (2434.300 us; speedup 1.0000x reference)
//
#include <hip/hip_runtime.h>
#include <math.h>

#define B_ 4
#define N_ 50000
#define E_ 800000
#define IN_ 128
#define H_ 4
#define D_ 32
#define HD_ 128
#define M_ (B_*N_)   // 200000 rows total

constexpr float GAT_SLOPE = 0.2f;
constexpr float ACT_SLOPE = 0.01f;
constexpr float BN_EPS = 1e-5f;

// ---- monotone float<->uint order map (for atomicMax on floats) ----
__device__ __forceinline__ unsigned fmap(float f) {
    unsigned u = __float_as_uint(f);
    return u ^ ((u >> 31) ? 0xFFFFFFFFu : 0x80000000u);
}
__device__ __forceinline__ float funmap(unsigned v) {
    unsigned u = (v & 0x80000000u) ? (v ^ 0x80000000u) : ~v;
    return __uint_as_float(u);
}

// ---- GEMM: feat[row, c] = sum_k xx[row,k] * W[k,c], rows = B*N, K=C=128 ----
__global__ __launch_bounds__(256) void gemm_kernel(const float* __restrict__ xx,
                                                   const float* __restrict__ W,
                                                   float* __restrict__ feat) {
    __shared__ float Ws[IN_ * HD_];   // 64 KB, [k][c]
    __shared__ float Xt[IN_][64];     // 32 KB, transposed [k][r]
    const int tid = threadIdx.x;
    const long row0 = (long)blockIdx.x * 64;

    for (int i = tid; i < IN_ * HD_ / 4; i += 256)
        ((float4*)Ws)[i] = ((const float4*)W)[i];
    for (int i = tid; i < 64 * IN_ / 4; i += 256) {
        int r = i >> 5;            // 32 float4 per row
        int k4 = (i & 31) << 2;
        float4 v = ((const float4*)(xx + (row0 + r) * IN_))[i & 31];
        Xt[k4 + 0][r] = v.x; Xt[k4 + 1][r] = v.y;
        Xt[k4 + 2][r] = v.z; Xt[k4 + 3][r] = v.w;
    }
    __syncthreads();

    const int cl = tid & 31;         // cols cl + 32*j  (j = head)
    const int r0 = (tid >> 5) * 8;   // 8 rows per thread
    float acc[8][4] = {};
    for (int k = 0; k < IN_; ++k) {
        float w0 = Ws[k * HD_ + cl];
        float w1 = Ws[k * HD_ + cl + 32];
        float w2 = Ws[k * HD_ + cl + 64];
        float w3 = Ws[k * HD_ + cl + 96];
        float4 xa = *(const float4*)&Xt[k][r0];
        float4 xb = *(const float4*)&Xt[k][r0 + 4];
        float xr[8] = {xa.x, xa.y, xa.z, xa.w, xb.x, xb.y, xb.z, xb.w};
#pragma unroll
        for (int i = 0; i < 8; ++i) {
            acc[i][0] = fmaf(xr[i], w0, acc[i][0]);
            acc[i][1] = fmaf(xr[i], w1, acc[i][1]);
            acc[i][2] = fmaf(xr[i], w2, acc[i][2]);
            acc[i][3] = fmaf(xr[i], w3, acc[i][3]);
        }
    }
#pragma unroll
    for (int i = 0; i < 8; ++i) {
        long r = row0 + r0 + i;
#pragma unroll
        for (int j = 0; j < 4; ++j)
            feat[r * HD_ + cl + 32 * j] = acc[i][j];
    }
}

// ---- el/er: per-node per-head dot of feat with attn vectors ----
__global__ __launch_bounds__(256) void elr_kernel(const float* __restrict__ feat,
                                                  const float* __restrict__ al,
                                                  const float* __restrict__ ar,
                                                  float* __restrict__ el,
                                                  float* __restrict__ er) {
    const int tid = threadIdx.x;
    const int c = tid & 127;
    const int h = c >> 5, d = c & 31;
    const int half = tid >> 7;
    for (long rp = blockIdx.x; rp < M_ / 2; rp += gridDim.x) {
        long row = rp * 2 + half;
        float f = feat[row * HD_ + c];
        float pl = f * al[c];
        float pr = f * ar[c];
        for (int o = 16; o; o >>= 1) {
            pl += __shfl_down(pl, o, 32);
            pr += __shfl_down(pr, o, 32);
        }
        if (d == 0) {
            el[row * H_ + h] = pl;
            er[row * H_ + h] = pr;
        }
    }
}

// ---- segment max over dst (atomicMax on order-mapped uints) ----
__global__ __launch_bounds__(256) void edge_max_kernel(const int* __restrict__ src,
                                                       const int* __restrict__ dst,
                                                       const float* __restrict__ el,
                                                       const float* __restrict__ er,
                                                       unsigned* __restrict__ m) {
    const long total = (long)B_ * E_ * H_;
    for (long i = (long)blockIdx.x * 256 + threadIdx.x; i < total;
         i += (long)gridDim.x * 256) {
        int h = (int)(i & 3);
        long be = i >> 2;
        int e = (int)(be % E_);
        int b = (int)(be / E_);
        int s = src[e], t = dst[e];
        float ev = el[((long)b * N_ + s) * H_ + h] + er[((long)b * N_ + t) * H_ + h];
        ev = ev >= 0.f ? ev : GAT_SLOPE * ev;
        atomicMax(&m[((long)b * N_ + t) * H_ + h], fmap(ev));
    }
}

// ---- per-edge: w = exp(e - m[dst]); accumulate w*feat[src] into acc[dst], w into denom[dst] ----
__global__ __launch_bounds__(256) void edge_accum_kernel(const int* __restrict__ src,
                                                         const int* __restrict__ dst,
                                                         const float* __restrict__ el,
                                                         const float* __restrict__ er,
                                                         const unsigned* __restrict__ m,
                                                         const float* __restrict__ feat,
                                                         float* __restrict__ acc,
                                                         float* __restrict__ denom) {
    const int tid = threadIdx.x;
    const int half = tid >> 7;      // 2 edges per block-iter
    const int c = tid & 127;
    const int h = c >> 5, d = c & 31;
    const long total = (long)B_ * E_;
    for (long p = (long)blockIdx.x * 2 + half; p < total; p += (long)gridDim.x * 2) {
        int e = (int)(p % E_);
        int b = (int)(p / E_);
        int s = src[e], t = dst[e];
        long bs = (long)b * N_ + s, bt = (long)b * N_ + t;
        float w = 0.f;
        if (d == 0) {
            float ev = el[bs * H_ + h] + er[bt * H_ + h];
            ev = ev >= 0.f ? ev : GAT_SLOPE * ev;
            unsigned mu = m[bt * H_ + h];
            float mv = (mu == 0u) ? 0.f : funmap(mu);   // untouched => zero-in-degree guard
            w = expf(ev - mv);
        }
        w = __shfl(w, 0, 32);
        float f = feat[bs * HD_ + c];
        atomicAdd(&acc[bt * HD_ + c], w * f);
        if (d == 0) atomicAdd(&denom[bt * H_ + h], w);
    }
}

// ---- divide by denom in place + per-channel sum/sumsq for BN ----
__global__ __launch_bounds__(256) void stats_kernel(float* __restrict__ acc,
                                                    const float* __restrict__ denom,
                                                    float* __restrict__ chsum) {
    const int tid = threadIdx.x;
    const int c = tid & 127;
    const int h = c >> 5;
    const int half = tid >> 7;
    float s = 0.f, s2 = 0.f;
    for (long rp = blockIdx.x; rp < M_ / 2; rp += gridDim.x) {
        long row = rp * 2 + half;
        float dn = denom[row * H_ + h];
        float v = acc[row * HD_ + c] / fmaxf(dn, 1e-9f);
        acc[row * HD_ + c] = v;
        s += v;
        s2 += v * v;
    }
    __shared__ float red[512];
    red[tid] = s; red[256 + tid] = s2;
    __syncthreads();
    if (tid < 128) {
        s = red[tid] + red[tid + 128];
        s2 = red[256 + tid] + red[256 + tid + 128];
        atomicAdd(&chsum[c], s);
        atomicAdd(&chsum[128 + c], s2);
    }
}

// ---- BN params: scale/shift per channel ----
__global__ void params_kernel(const float* __restrict__ chsum,
                              const float* __restrict__ gamma,
                              const float* __restrict__ beta,
                              float* __restrict__ ss) {
    int c = threadIdx.x;  // 128 threads
    float mean = chsum[c] / (float)M_;
    float var = chsum[128 + c] / (float)M_ - mean * mean;
    float rstd = rsqrtf(var + BN_EPS);
    float sc = rstd * gamma[c];
    ss[c] = sc;
    ss[128 + c] = beta[c] - mean * sc;
}

// ---- normalize + final leaky relu, in place on d_out ----
__global__ __launch_bounds__(256) void norm_kernel(float* __restrict__ out,
                                                   const float* __restrict__ ss) {
    __shared__ float s_sc[128], s_sh[128];
    if (threadIdx.x < 128) {
        s_sc[threadIdx.x] = ss[threadIdx.x];
        s_sh[threadIdx.x] = ss[128 + threadIdx.x];
    }
    __syncthreads();
    const long total4 = (long)M_ * HD_ / 4;
    for (long i = (long)blockIdx.x * 256 + threadIdx.x; i < total4;
         i += (long)gridDim.x * 256) {
        float4 v = ((float4*)out)[i];
        int c = (int)((i & 31) << 2);   // (i*4) % 128
        float4 r;
        r.x = v.x * s_sc[c + 0] + s_sh[c + 0];
        r.y = v.y * s_sc[c + 1] + s_sh[c + 1];
        r.z = v.z * s_sc[c + 2] + s_sh[c + 2];
        r.w = v.w * s_sc[c + 3] + s_sh[c + 3];
        r.x = r.x >= 0.f ? r.x : ACT_SLOPE * r.x;
        r.y = r.y >= 0.f ? r.y : ACT_SLOPE * r.y;
        r.z = r.z >= 0.f ? r.z : ACT_SLOPE * r.z;
        r.w = r.w >= 0.f ? r.w : ACT_SLOPE * r.w;
        ((float4*)out)[i] = r;
    }
}

extern "C" void kernel_launch(void* const* d_in, const int* in_sizes, int n_in,
                              void* d_out, int out_size, void* d_ws, size_t ws_size,
                              hipStream_t stream) {
    const float* xx    = (const float*)d_in[0];
    const float* W     = (const float*)d_in[1];
    const float* al    = (const float*)d_in[2];
    const float* ar    = (const float*)d_in[3];
    const float* gamma = (const float*)d_in[4];
    const float* beta  = (const float*)d_in[5];
    const int*   src   = (const int*)d_in[6];
    const int*   dst   = (const int*)d_in[7];
    float* out = (float*)d_out;

    char* ws = (char*)d_ws;
    float*    feat  = (float*)ws;    ws += (size_t)M_ * HD_ * 4;  // 102.4 MB
    float*    el    = (float*)ws;    ws += (size_t)M_ * H_ * 4;   // 3.2 MB
    float*    er    = (float*)ws;    ws += (size_t)M_ * H_ * 4;
    unsigned* m     = (unsigned*)ws; ws += (size_t)M_ * H_ * 4;
    float*    denom = (float*)ws;    ws += (size_t)M_ * H_ * 4;
    float*    chsum = (float*)ws;    ws += 256 * 4;
    float*    ss    = (float*)ws;    ws += 256 * 4;

    hipMemsetAsync(m,     0, (size_t)M_ * H_ * 4, stream);
    hipMemsetAsync(denom, 0, (size_t)M_ * H_ * 4, stream);
    hipMemsetAsync(chsum, 0, 256 * 4, stream);
    hipMemsetAsync(out,   0, (size_t)M_ * HD_ * 4, stream);

    gemm_kernel<<<M_ / 64, 256, 0, stream>>>(xx, W, feat);
    elr_kernel<<<4096, 256, 0, stream>>>(feat, al, ar, el, er);
    edge_max_kernel<<<8192, 256, 0, stream>>>(src, dst, el, er, m);
    edge_accum_kernel<<<8192, 256, 0, stream>>>(src, dst, el, er, m, feat, out, denom);
    stats_kernel<<<2048, 256, 0, stream>>>(out, denom, chsum);
    params_kernel<<<1, 128, 0, stream>>>(chsum, gamma, beta, ss);
    norm_kernel<<<4096, 256, 0, stream>>>(out, ss);
}

// Round 2
// 991.856 us; speedup vs baseline: 2.4543x; 2.4543x over previous
//
#include <hip/hip_runtime.h>
#include <math.h>

#define B_ 4
#define N_ 50000
#define E_ 800000
#define IN_ 128
#define H_ 4
#define D_ 32
#define HD_ 128
#define M_ (B_*N_)   // 200000 rows total

constexpr float GAT_SLOPE = 0.2f;
constexpr float ACT_SLOPE = 0.01f;
constexpr float BN_EPS = 1e-5f;

// ---- GEMM: feat[row, c] = sum_k xx[row,k] * W[k,c], rows = B*N, K=C=128 ----
__global__ __launch_bounds__(256) void gemm_kernel(const float* __restrict__ xx,
                                                   const float* __restrict__ W,
                                                   float* __restrict__ feat) {
    __shared__ float Ws[IN_ * HD_];   // 64 KB, [k][c]
    __shared__ float Xt[IN_][64];     // 32 KB, transposed [k][r]
    const int tid = threadIdx.x;
    const long row0 = (long)blockIdx.x * 64;

    for (int i = tid; i < IN_ * HD_ / 4; i += 256)
        ((float4*)Ws)[i] = ((const float4*)W)[i];
    for (int i = tid; i < 64 * IN_ / 4; i += 256) {
        int r = i >> 5;            // 32 float4 per row
        int k4 = (i & 31) << 2;
        float4 v = ((const float4*)(xx + (row0 + r) * IN_))[i & 31];
        Xt[k4 + 0][r] = v.x; Xt[k4 + 1][r] = v.y;
        Xt[k4 + 2][r] = v.z; Xt[k4 + 3][r] = v.w;
    }
    __syncthreads();

    const int cl = tid & 31;         // cols cl + 32*j  (j = head)
    const int r0 = (tid >> 5) * 8;   // 8 rows per thread
    float acc[8][4] = {};
    for (int k = 0; k < IN_; ++k) {
        float w0 = Ws[k * HD_ + cl];
        float w1 = Ws[k * HD_ + cl + 32];
        float w2 = Ws[k * HD_ + cl + 64];
        float w3 = Ws[k * HD_ + cl + 96];
        float4 xa = *(const float4*)&Xt[k][r0];
        float4 xb = *(const float4*)&Xt[k][r0 + 4];
        float xr[8] = {xa.x, xa.y, xa.z, xa.w, xb.x, xb.y, xb.z, xb.w};
#pragma unroll
        for (int i = 0; i < 8; ++i) {
            acc[i][0] = fmaf(xr[i], w0, acc[i][0]);
            acc[i][1] = fmaf(xr[i], w1, acc[i][1]);
            acc[i][2] = fmaf(xr[i], w2, acc[i][2]);
            acc[i][3] = fmaf(xr[i], w3, acc[i][3]);
        }
    }
#pragma unroll
    for (int i = 0; i < 8; ++i) {
        long r = row0 + r0 + i;
#pragma unroll
        for (int j = 0; j < 4; ++j)
            feat[r * HD_ + cl + 32 * j] = acc[i][j];
    }
}

// ---- el/er: per-node per-head dot of feat with attn vectors ----
__global__ __launch_bounds__(256) void elr_kernel(const float* __restrict__ feat,
                                                  const float* __restrict__ al,
                                                  const float* __restrict__ ar,
                                                  float* __restrict__ el,
                                                  float* __restrict__ er) {
    const int tid = threadIdx.x;
    const int c = tid & 127;
    const int h = c >> 5, d = c & 31;
    const int half = tid >> 7;
    for (long rp = blockIdx.x; rp < M_ / 2; rp += gridDim.x) {
        long row = rp * 2 + half;
        float f = feat[row * HD_ + c];
        float pl = f * al[c];
        float pr = f * ar[c];
        for (int o = 16; o; o >>= 1) {
            pl += __shfl_down(pl, o, 32);
            pr += __shfl_down(pr, o, 32);
        }
        if (d == 0) {
            el[row * H_ + h] = pl;
            er[row * H_ + h] = pr;
        }
    }
}

// ---- CSR build step 1: in-degree histogram over dst ----
__global__ __launch_bounds__(256) void hist_kernel(const int* __restrict__ dst,
                                                   int* __restrict__ counts) {
    for (int e = blockIdx.x * 256 + threadIdx.x; e < E_; e += gridDim.x * 256)
        atomicAdd(&counts[dst[e]], 1);
}

// ---- CSR build step 2: exclusive scan of counts -> offsets (+cursor copy) ----
__global__ __launch_bounds__(1024) void scan_kernel(const int* __restrict__ counts,
                                                    int* __restrict__ offsets,
                                                    int* __restrict__ cursor) {
    __shared__ int part[1024];
    const int tid = threadIdx.x;
    const int CH = (N_ + 1023) / 1024;   // 49
    const int base = tid * CH;
    int s = 0;
    for (int i = 0; i < CH; ++i) {
        int idx = base + i;
        if (idx < N_) s += counts[idx];
    }
    part[tid] = s;
    __syncthreads();
    for (int off = 1; off < 1024; off <<= 1) {
        int v = (tid >= off) ? part[tid - off] : 0;
        __syncthreads();
        part[tid] += v;
        __syncthreads();
    }
    int run = (tid == 0) ? 0 : part[tid - 1];
    for (int i = 0; i < CH; ++i) {
        int idx = base + i;
        if (idx < N_) {
            offsets[idx] = run;
            cursor[idx] = run;
            run += counts[idx];
        }
    }
    if (tid == 0) offsets[N_] = part[1023];   // == E_
}

// ---- CSR build step 3: scatter src ids into dst-sorted order ----
__global__ __launch_bounds__(256) void scatter_kernel(const int* __restrict__ src,
                                                      const int* __restrict__ dst,
                                                      int* __restrict__ cursor,
                                                      int* __restrict__ srcs) {
    for (int e = blockIdx.x * 256 + threadIdx.x; e < E_; e += gridDim.x * 256) {
        int pos = atomicAdd(&cursor[dst[e]], 1);
        srcs[pos] = src[e];
    }
}

// ---- per-(b,node) softmax + aggregation, atomic-free, writes out/denom in one go ----
__global__ __launch_bounds__(128) void aggregate_kernel(const int* __restrict__ offsets,
                                                        const int* __restrict__ srcs,
                                                        const float* __restrict__ el,
                                                        const float* __restrict__ er,
                                                        const float* __restrict__ feat,
                                                        float* __restrict__ out) {
    const int t = threadIdx.x;       // channel 0..127
    const int h = t >> 5;            // head
    const int lane = t & 31;
    const long bn = blockIdx.x;      // b*N + n
    const int b = (int)(bn / N_);
    const int n = (int)(bn % N_);
    const long bbase = (long)b * N_;
    const int beg = offsets[n], end = offsets[n + 1];

    const float ern = er[(bbase + n) * H_ + h];

    // pass A: per-head max over in-edges
    float mx = -INFINITY;
    for (int i = beg + lane; i < end; i += 32) {
        int s = srcs[i];
        float ev = el[(bbase + s) * H_ + h] + ern;
        ev = ev >= 0.f ? ev : GAT_SLOPE * ev;
        mx = fmaxf(mx, ev);
    }
#pragma unroll
    for (int o = 16; o; o >>= 1) mx = fmaxf(mx, __shfl_xor(mx, o, 32));

    // pass B: accumulate exp(e-m)*feat[src] and denom (every lane tracks full denom)
    float acc = 0.f, denom = 0.f;
    int i = beg;
    for (; i + 1 < end; i += 2) {
        int s0 = srcs[i], s1 = srcs[i + 1];
        float e0 = el[(bbase + s0) * H_ + h] + ern;
        float e1 = el[(bbase + s1) * H_ + h] + ern;
        float f0 = feat[(bbase + s0) * HD_ + t];
        float f1 = feat[(bbase + s1) * HD_ + t];
        e0 = e0 >= 0.f ? e0 : GAT_SLOPE * e0;
        e1 = e1 >= 0.f ? e1 : GAT_SLOPE * e1;
        float w0 = __expf(e0 - mx);
        float w1 = __expf(e1 - mx);
        acc = fmaf(w0, f0, acc);
        acc = fmaf(w1, f1, acc);
        denom += w0 + w1;
    }
    if (i < end) {
        int s0 = srcs[i];
        float e0 = el[(bbase + s0) * H_ + h] + ern;
        float f0 = feat[(bbase + s0) * HD_ + t];
        e0 = e0 >= 0.f ? e0 : GAT_SLOPE * e0;
        float w0 = __expf(e0 - mx);
        acc = fmaf(w0, f0, acc);
        denom += w0;
    }
    out[bn * HD_ + t] = acc / fmaxf(denom, 1e-9f);
}

// ---- per-channel sum/sumsq for BN (read-only) ----
__global__ __launch_bounds__(256) void stats_kernel(const float* __restrict__ out,
                                                    float* __restrict__ chsum) {
    const int tid = threadIdx.x;
    const int c = tid & 127;
    const int half = tid >> 7;
    float s = 0.f, s2 = 0.f;
    for (long rp = blockIdx.x; rp < M_ / 2; rp += gridDim.x) {
        long row = rp * 2 + half;
        float v = out[row * HD_ + c];
        s += v;
        s2 += v * v;
    }
    __shared__ float red[512];
    red[tid] = s; red[256 + tid] = s2;
    __syncthreads();
    if (tid < 128) {
        s = red[tid] + red[tid + 128];
        s2 = red[256 + tid] + red[256 + tid + 128];
        atomicAdd(&chsum[c], s);
        atomicAdd(&chsum[128 + c], s2);
    }
}

// ---- BN params: scale/shift per channel ----
__global__ void params_kernel(const float* __restrict__ chsum,
                              const float* __restrict__ gamma,
                              const float* __restrict__ beta,
                              float* __restrict__ ss) {
    int c = threadIdx.x;  // 128 threads
    float mean = chsum[c] / (float)M_;
    float var = chsum[128 + c] / (float)M_ - mean * mean;
    float rstd = rsqrtf(var + BN_EPS);
    float sc = rstd * gamma[c];
    ss[c] = sc;
    ss[128 + c] = beta[c] - mean * sc;
}

// ---- normalize + final leaky relu, in place on d_out ----
__global__ __launch_bounds__(256) void norm_kernel(float* __restrict__ out,
                                                   const float* __restrict__ ss) {
    __shared__ float s_sc[128], s_sh[128];
    if (threadIdx.x < 128) {
        s_sc[threadIdx.x] = ss[threadIdx.x];
        s_sh[threadIdx.x] = ss[128 + threadIdx.x];
    }
    __syncthreads();
    const long total4 = (long)M_ * HD_ / 4;
    for (long i = (long)blockIdx.x * 256 + threadIdx.x; i < total4;
         i += (long)gridDim.x * 256) {
        float4 v = ((float4*)out)[i];
        int c = (int)((i & 31) << 2);   // (i*4) % 128
        float4 r;
        r.x = v.x * s_sc[c + 0] + s_sh[c + 0];
        r.y = v.y * s_sc[c + 1] + s_sh[c + 1];
        r.z = v.z * s_sc[c + 2] + s_sh[c + 2];
        r.w = v.w * s_sc[c + 3] + s_sh[c + 3];
        r.x = r.x >= 0.f ? r.x : ACT_SLOPE * r.x;
        r.y = r.y >= 0.f ? r.y : ACT_SLOPE * r.y;
        r.z = r.z >= 0.f ? r.z : ACT_SLOPE * r.z;
        r.w = r.w >= 0.f ? r.w : ACT_SLOPE * r.w;
        ((float4*)out)[i] = r;
    }
}

extern "C" void kernel_launch(void* const* d_in, const int* in_sizes, int n_in,
                              void* d_out, int out_size, void* d_ws, size_t ws_size,
                              hipStream_t stream) {
    const float* xx    = (const float*)d_in[0];
    const float* W     = (const float*)d_in[1];
    const float* al    = (const float*)d_in[2];
    const float* ar    = (const float*)d_in[3];
    const float* gamma = (const float*)d_in[4];
    const float* beta  = (const float*)d_in[5];
    const int*   src   = (const int*)d_in[6];
    const int*   dst   = (const int*)d_in[7];
    float* out = (float*)d_out;

    char* ws = (char*)d_ws;
    float* feat    = (float*)ws;  ws += (size_t)M_ * HD_ * 4;   // 102.4 MB
    float* el      = (float*)ws;  ws += (size_t)M_ * H_ * 4;    // 3.2 MB
    float* er      = (float*)ws;  ws += (size_t)M_ * H_ * 4;
    int*   counts  = (int*)ws;    ws += (size_t)N_ * 4;
    int*   offsets = (int*)ws;    ws += (size_t)(N_ + 1) * 4;
    int*   cursor  = (int*)ws;    ws += (size_t)N_ * 4;
    int*   srcs    = (int*)ws;    ws += (size_t)E_ * 4;         // 3.2 MB
    float* chsum   = (float*)ws;  ws += 256 * 4;
    float* ss      = (float*)ws;  ws += 256 * 4;

    hipMemsetAsync(counts, 0, (size_t)N_ * 4, stream);
    hipMemsetAsync(chsum, 0, 256 * 4, stream);

    gemm_kernel<<<M_ / 64, 256, 0, stream>>>(xx, W, feat);
    elr_kernel<<<4096, 256, 0, stream>>>(feat, al, ar, el, er);
    hist_kernel<<<2048, 256, 0, stream>>>(dst, counts);
    scan_kernel<<<1, 1024, 0, stream>>>(counts, offsets, cursor);
    scatter_kernel<<<2048, 256, 0, stream>>>(src, dst, cursor, srcs);
    aggregate_kernel<<<M_, 128, 0, stream>>>(offsets, srcs, el, er, feat, out);
    stats_kernel<<<2048, 256, 0, stream>>>(out, chsum);
    params_kernel<<<1, 128, 0, stream>>>(chsum, gamma, beta, ss);
    norm_kernel<<<4096, 256, 0, stream>>>(out, ss);
}